// Round 4
// baseline (1169.718 us; speedup 1.0000x reference)
//
#include <hip/hip_runtime.h>

// Problem constants (from reference setup_inputs)
#define NU 8192      // NUM_USER
#define NI 16384     // NUM_ITEM
#define NH 64        // NUM_HIDDEN
#define TM 128       // tile rows (users)
#define TN 128       // tile cols (items)
#define KP 32        // k-elements staged per phase (2 phases over NH=64)
#define MASK_BLOCKS 8

typedef float v4 __attribute__((ext_vector_type(4)));  // native vec for NT stores

// ---------------------------------------------------------------------------
// 1) zero the mask scratch (d_ws poisoned 0xAA each call) + write ratio
// ---------------------------------------------------------------------------
__global__ void init_kernel(unsigned int* __restrict__ p, int nwords,
                            float* __restrict__ ratio) {
    int i = blockIdx.x * blockDim.x + threadIdx.x;
    if (i < nwords) p[i] = 0u;
    if (i == 0) *ratio = 671.08864f;   // U*I/NNZ = 134217728/200000
}

// ---------------------------------------------------------------------------
// 2) build user/item row masks in per-block LDS, merge via word atomicOr.
//    Replaces 400k random global byte-RMWs (24KB region thrashing across
//    8 non-coherent XCD L2s) with LDS byte sets + 49k word atomics.
// ---------------------------------------------------------------------------
__global__ __launch_bounds__(256) void build_masks_kernel(
    const int* __restrict__ idx,
    unsigned int* __restrict__ mw,   // 6144 words: um bytes then im bytes
    int nnz) {
    __shared__ unsigned char lm[NU + NI];   // 24 KB local byte masks
    unsigned int* lw = (unsigned int*)lm;
    const int tid = threadIdx.x;

    for (int j = tid; j < (NU + NI) / 4; j += 256) lw[j] = 0u;
    __syncthreads();

    const int chunk = (nnz + MASK_BLOCKS - 1) / MASK_BLOCKS;
    const int k0 = blockIdx.x * chunk;
    const int k1 = min(nnz, k0 + chunk);
    for (int k = k0 + tid; k < k1; k += 256) {
        lm[idx[k]]            = 1;   // user id   (benign in-block race)
        lm[NU + idx[nnz + k]] = 1;   // item id
    }
    __syncthreads();

    for (int j = tid; j < (NU + NI) / 4; j += 256) {
        unsigned int w = lw[j];
        if (w) atomicOr(&mw[j], w);  // skip zero words (half of im is cold)
    }
}

// ---------------------------------------------------------------------------
// 3) masked GEMM (UNCHANGED — control). K split into two 32-wide
//    staging phases, 32 KB LDS, label-zero NT stores fired before FMA loop.
// ---------------------------------------------------------------------------
__global__ __launch_bounds__(256, 4) void gemm_kernel(
    const float* __restrict__ A,   // [NU][NH] embed_user
    const float* __restrict__ B,   // [NI][NH] embed_item
    const unsigned char* __restrict__ um,
    const unsigned char* __restrict__ im,
    float* __restrict__ pred,      // [NU][NI]
    float* __restrict__ label)     // [NU][NI]
{
    __shared__ float As[KP * TM];  // 16 KB
    __shared__ float Bs[KP * TN];  // 16 KB

    const int tid = threadIdx.x;
    const int c0 = blockIdx.x * TN;
    const int r0 = blockIdx.y * TM;

    const int any = __syncthreads_or((tid < TN) && (im[c0 + tid] != 0));

    v4* __restrict__ pred4 = (v4*)pred;
    v4* __restrict__ lab4  = (v4*)label;
    const v4 z4 = (v4){0.f, 0.f, 0.f, 0.f};

    if (!any) {
        // whole tile zero: stream zeros, skip compute
#pragma unroll
        for (int i = 0; i < TM * TN / 4 / 256; ++i) {
            int f   = i * 256 + tid;
            int row = f >> 5;
            int cv  = f & 31;
            size_t o = (size_t)(r0 + row) * (NI / 4) + (size_t)(c0 >> 2) + cv;
            __builtin_nontemporal_store(z4, &pred4[o]);
            __builtin_nontemporal_store(z4, &lab4[o]);
        }
        return;
    }

    const float4* A4 = (const float4*)A;
    const float4* B4 = (const float4*)B;
    const float4* As4 = (const float4*)As;   // 32 float4 per k-row
    const float4* Bs4 = (const float4*)Bs;

    const int tx = tid & 15;
    const int ty = tid >> 4;

    float acc[2][4][2][4];
#pragma unroll
    for (int rg = 0; rg < 2; ++rg)
#pragma unroll
        for (int i = 0; i < 4; ++i)
#pragma unroll
            for (int cg = 0; cg < 2; ++cg)
#pragma unroll
                for (int j = 0; j < 4; ++j) acc[rg][i][cg][j] = 0.f;

#pragma unroll
    for (int p = 0; p < 2; ++p) {
        if (p) __syncthreads();   // phase-0 LDS reads complete before restage

        // ---- stage A,B k-slices (masked) into swizzled k-major LDS ----
#pragma unroll
        for (int t = 0; t < 4; ++t) {
            int idx4 = tid + t * 256;   // 0..1023
            int m    = idx4 >> 3;       // 0..127 (row within tile)
            int kv   = idx4 & 7;        // local float4 index along k
            int base = (4 * kv) * TM + 4 * ((m >> 2) ^ kv) + (m & 3);
            {
                float msk = um[r0 + m] ? 1.f : 0.f;
                float4 v = A4[(size_t)(r0 + m) * (NH / 4) + p * (KP / 4) + kv];
                As[base]           = v.x * msk;
                As[base + TM]      = v.y * msk;
                As[base + 2 * TM]  = v.z * msk;
                As[base + 3 * TM]  = v.w * msk;
            }
            {
                float msk = im[c0 + m] ? 1.f : 0.f;
                float4 v = B4[(size_t)(c0 + m) * (NH / 4) + p * (KP / 4) + kv];
                Bs[base]           = v.x * msk;
                Bs[base + TN]      = v.y * msk;
                Bs[base + 2 * TN]  = v.z * msk;
                Bs[base + 3 * TN]  = v.w * msk;
            }
        }
        __syncthreads();

        if (p == 0) {
            // ---- fire label-zero NT stores; they drain during the FMA loop
#pragma unroll
            for (int i = 0; i < TM * TN / 4 / 256; ++i) {
                int f   = i * 256 + tid;
                int row = f >> 5;
                int cv  = f & 31;
                size_t o = (size_t)(r0 + row) * (NI / 4) + (size_t)(c0 >> 2) + cv;
                __builtin_nontemporal_store(z4, &lab4[o]);
            }
        }

        // ---- FMA over this phase's 32 k-values ----
#pragma unroll 2
        for (int kv = 0; kv < KP / 4; ++kv) {
            const int ta = ty ^ kv;
            const int tb = tx ^ kv;
            const int kb = kv * 4 * 32;
#pragma unroll
            for (int r = 0; r < 4; ++r) {
                float4 a0 = As4[kb + r * 32 + ta];
                float4 a1 = As4[kb + r * 32 + 16 + ta];
                float4 b0 = Bs4[kb + r * 32 + tb];
                float4 b1 = Bs4[kb + r * 32 + 16 + tb];
                float ar[2][4] = {{a0.x, a0.y, a0.z, a0.w}, {a1.x, a1.y, a1.z, a1.w}};
                float br[2][4] = {{b0.x, b0.y, b0.z, b0.w}, {b1.x, b1.y, b1.z, b1.w}};
#pragma unroll
                for (int rg = 0; rg < 2; ++rg)
#pragma unroll
                    for (int i = 0; i < 4; ++i)
#pragma unroll
                        for (int cg = 0; cg < 2; ++cg)
#pragma unroll
                            for (int j = 0; j < 4; ++j)
                                acc[rg][i][cg][j] += ar[rg][i] * br[cg][j];
            }
        }
    }

    // ---- epilogue: NT-write pred tile ----
#pragma unroll
    for (int rg = 0; rg < 2; ++rg)
#pragma unroll
        for (int i = 0; i < 4; ++i) {
            int row = r0 + rg * 64 + ty * 4 + i;
            size_t rb = (size_t)row * (NI / 4);
#pragma unroll
            for (int cg = 0; cg < 2; ++cg) {
                size_t cv = (size_t)((c0 + cg * 64 + tx * 4) >> 2);
                v4 v = (v4){acc[rg][i][cg][0], acc[rg][i][cg][1],
                            acc[rg][i][cg][2], acc[rg][i][cg][3]};
                __builtin_nontemporal_store(v, &pred4[rb + cv]);
            }
        }
}

// ---------------------------------------------------------------------------
// 4) scatter-add ratings into label (duplicates sum correctly)
// ---------------------------------------------------------------------------
__global__ void scatter_kernel(const int* __restrict__ idx,
                               const float* __restrict__ r,
                               float* __restrict__ label, int nnz) {
    int k = blockIdx.x * blockDim.x + threadIdx.x;
    if (k < nnz) {
        int u  = idx[k];
        int it = idx[nnz + k];
        atomicAdd(&label[(size_t)u * NI + it], r[k]);
    }
}

extern "C" void kernel_launch(void* const* d_in, const int* in_sizes, int n_in,
                              void* d_out, int out_size, void* d_ws, size_t ws_size,
                              hipStream_t stream) {
    const float* A   = (const float*)d_in[0];
    const float* B   = (const float*)d_in[1];
    const int*   idx = (const int*)d_in[2];
    const float* r   = (const float*)d_in[3];
    const int nnz = in_sizes[3];

    float* out   = (float*)d_out;
    float* pred  = out;
    float* label = out + (size_t)NU * NI;
    float* ratio = out + 2 * (size_t)NU * NI;

    unsigned char* um = (unsigned char*)d_ws;
    unsigned char* im = um + NU;

    const int mask_words = (NU + NI) / 4;
    init_kernel<<<(mask_words + 255) / 256, 256, 0, stream>>>(
        (unsigned int*)d_ws, mask_words, ratio);
    build_masks_kernel<<<MASK_BLOCKS, 256, 0, stream>>>(
        idx, (unsigned int*)d_ws, nnz);

    dim3 grid(NI / TN, NU / TM);
    gemm_kernel<<<grid, 256, 0, stream>>>(A, B, um, im, pred, label);

    scatter_kernel<<<(nnz + 255) / 256, 256, 0, stream>>>(idx, r, label, nnz);
}

// Round 6
// 1114.691 us; speedup vs baseline: 1.0494x; 1.0494x over previous
//
#include <hip/hip_runtime.h>

// Problem constants (from reference setup_inputs)
#define NU 8192      // NUM_USER
#define NI 16384     // NUM_ITEM
#define NH 64        // NUM_HIDDEN
#define TM 128       // tile rows (users)
#define TN 128       // tile cols (items)
#define KP 32        // k-elements staged per phase (2 phases over NH=64)

typedef float v4 __attribute__((ext_vector_type(4)));  // native vec for NT stores

// ---------------------------------------------------------------------------
// 1) zero the mask scratch (d_ws poisoned 0xAA each call) + write ratio
// ---------------------------------------------------------------------------
__global__ void init_kernel(unsigned int* __restrict__ p, int nwords,
                            float* __restrict__ ratio) {
    int i = blockIdx.x * blockDim.x + threadIdx.x;
    if (i < nwords) p[i] = 0u;
    if (i == 0) *ratio = 671.08864f;   // U*I/NNZ = 134217728/200000
}

// ---------------------------------------------------------------------------
// 2) build user/item row masks — global-byte version (measured fastest:
//    1123.5 vs 1169.7 with the 8-block LDS variant). Benign same-value
//    races; 782 blocks keep it latency-hidden.
// ---------------------------------------------------------------------------
__global__ void build_masks_kernel(const int* __restrict__ idx,
                                   unsigned char* __restrict__ um,
                                   unsigned char* __restrict__ im, int nnz) {
    int k = blockIdx.x * blockDim.x + threadIdx.x;
    if (k < nnz) {
        um[idx[k]]       = 1;
        im[idx[nnz + k]] = 1;
    }
}

// ---------------------------------------------------------------------------
// 3) masked GEMM, K split into two 32-wide phases; phase-1 tiles are
//    PREFETCHED INTO REGISTERS during phase-0 FMA, so the phase boundary is
//    ds_write + barrier instead of a global-load round-trip. Label-zero NT
//    stores fire after the prefetch loads are issued; they drain under FMA.
// ---------------------------------------------------------------------------
__global__ __launch_bounds__(256, 3) void gemm_kernel(
    const float* __restrict__ A,   // [NU][NH] embed_user
    const float* __restrict__ B,   // [NI][NH] embed_item
    const unsigned char* __restrict__ um,
    const unsigned char* __restrict__ im,
    float* __restrict__ pred,      // [NU][NI]
    float* __restrict__ label)     // [NU][NI]
{
    __shared__ float As[KP * TM];  // 16 KB
    __shared__ float Bs[KP * TN];  // 16 KB

    const int tid = threadIdx.x;
    const int c0 = blockIdx.x * TN;
    const int r0 = blockIdx.y * TM;

    const int any = __syncthreads_or((tid < TN) && (im[c0 + tid] != 0));

    v4* __restrict__ pred4 = (v4*)pred;
    v4* __restrict__ lab4  = (v4*)label;
    const v4 z4 = (v4){0.f, 0.f, 0.f, 0.f};

    if (!any) {
        // whole tile zero: stream zeros, skip compute
#pragma unroll
        for (int i = 0; i < TM * TN / 4 / 256; ++i) {
            int f   = i * 256 + tid;
            int row = f >> 5;
            int cv  = f & 31;
            size_t o = (size_t)(r0 + row) * (NI / 4) + (size_t)(c0 >> 2) + cv;
            __builtin_nontemporal_store(z4, &pred4[o]);
            __builtin_nontemporal_store(z4, &lab4[o]);
        }
        return;
    }

    const float4* A4 = (const float4*)A;
    const float4* B4 = (const float4*)B;
    const float4* As4 = (const float4*)As;   // 32 float4 per k-row
    const float4* Bs4 = (const float4*)Bs;

    // staging geometry: idx4 = tid + t*256 -> m = (tid>>3)+32t, kv = tid&7
    const int ms  = tid >> 3;   // 0..31
    const int kvL = tid & 7;    // float4-k within a 32-wide phase

    // hoisted row masks for this thread's 4 staged rows (A and B)
    float amsk[4], bmsk[4];
#pragma unroll
    for (int t = 0; t < 4; ++t) {
        amsk[t] = um[r0 + ms + 32 * t] ? 1.f : 0.f;
        bmsk[t] = im[c0 + ms + 32 * t] ? 1.f : 0.f;
    }

    // ---- stage phase 0 (k = 0..31) straight to LDS ----
#pragma unroll
    for (int t = 0; t < 4; ++t) {
        int m    = ms + 32 * t;
        int base = (4 * kvL) * TM + 4 * ((m >> 2) ^ kvL) + (m & 3);
        float4 va = A4[(size_t)(r0 + m) * (NH / 4) + kvL];
        float4 vb = B4[(size_t)(c0 + m) * (NH / 4) + kvL];
        As[base]          = va.x * amsk[t];
        As[base + TM]     = va.y * amsk[t];
        As[base + 2 * TM] = va.z * amsk[t];
        As[base + 3 * TM] = va.w * amsk[t];
        Bs[base]          = vb.x * bmsk[t];
        Bs[base + TN]     = vb.y * bmsk[t];
        Bs[base + 2 * TN] = vb.z * bmsk[t];
        Bs[base + 3 * TN] = vb.w * bmsk[t];
    }
    __syncthreads();

    // ---- issue phase-1 prefetch loads FIRST (k = 32..63) ----
    float4 pa[4], pb[4];
#pragma unroll
    for (int t = 0; t < 4; ++t) {
        int m = ms + 32 * t;
        pa[t] = A4[(size_t)(r0 + m) * (NH / 4) + (KP / 4) + kvL];
        pb[t] = B4[(size_t)(c0 + m) * (NH / 4) + (KP / 4) + kvL];
    }

    // ---- then fire label-zero NT stores; both drain under the FMA loop ----
#pragma unroll
    for (int i = 0; i < TM * TN / 4 / 256; ++i) {
        int f   = i * 256 + tid;
        int row = f >> 5;
        int cv  = f & 31;
        size_t o = (size_t)(r0 + row) * (NI / 4) + (size_t)(c0 >> 2) + cv;
        __builtin_nontemporal_store(z4, &lab4[o]);
    }

    const int tx = tid & 15;
    const int ty = tid >> 4;

    float acc[2][4][2][4];
#pragma unroll
    for (int rg = 0; rg < 2; ++rg)
#pragma unroll
        for (int i = 0; i < 4; ++i)
#pragma unroll
            for (int cg = 0; cg < 2; ++cg)
#pragma unroll
                for (int j = 0; j < 4; ++j) acc[rg][i][cg][j] = 0.f;

#pragma unroll
    for (int p = 0; p < 2; ++p) {
        if (p) {
            // phase boundary: regs -> LDS (no global latency here)
            __syncthreads();   // all phase-0 LDS reads done
#pragma unroll
            for (int t = 0; t < 4; ++t) {
                int m    = ms + 32 * t;
                int base = (4 * kvL) * TM + 4 * ((m >> 2) ^ kvL) + (m & 3);
                As[base]          = pa[t].x * amsk[t];
                As[base + TM]     = pa[t].y * amsk[t];
                As[base + 2 * TM] = pa[t].z * amsk[t];
                As[base + 3 * TM] = pa[t].w * amsk[t];
                Bs[base]          = pb[t].x * bmsk[t];
                Bs[base + TN]     = pb[t].y * bmsk[t];
                Bs[base + 2 * TN] = pb[t].z * bmsk[t];
                Bs[base + 3 * TN] = pb[t].w * bmsk[t];
            }
            __syncthreads();
        }

        // ---- FMA over this phase's 32 k-values ----
#pragma unroll 2
        for (int kv = 0; kv < KP / 4; ++kv) {
            const int ta = ty ^ kv;
            const int tb = tx ^ kv;
            const int kb = kv * 4 * 32;
#pragma unroll
            for (int r = 0; r < 4; ++r) {
                float4 a0 = As4[kb + r * 32 + ta];
                float4 a1 = As4[kb + r * 32 + 16 + ta];
                float4 b0 = Bs4[kb + r * 32 + tb];
                float4 b1 = Bs4[kb + r * 32 + 16 + tb];
                float ar[2][4] = {{a0.x, a0.y, a0.z, a0.w}, {a1.x, a1.y, a1.z, a1.w}};
                float br[2][4] = {{b0.x, b0.y, b0.z, b0.w}, {b1.x, b1.y, b1.z, b1.w}};
#pragma unroll
                for (int rg = 0; rg < 2; ++rg)
#pragma unroll
                    for (int i = 0; i < 4; ++i)
#pragma unroll
                        for (int cg = 0; cg < 2; ++cg)
#pragma unroll
                            for (int j = 0; j < 4; ++j)
                                acc[rg][i][cg][j] += ar[rg][i] * br[cg][j];
            }
        }
    }

    // ---- epilogue: NT-write pred tile ----
#pragma unroll
    for (int rg = 0; rg < 2; ++rg)
#pragma unroll
        for (int i = 0; i < 4; ++i) {
            int row = r0 + rg * 64 + ty * 4 + i;
            size_t rb = (size_t)row * (NI / 4);
#pragma unroll
            for (int cg = 0; cg < 2; ++cg) {
                size_t cv = (size_t)((c0 + cg * 64 + tx * 4) >> 2);
                v4 v = (v4){acc[rg][i][cg][0], acc[rg][i][cg][1],
                            acc[rg][i][cg][2], acc[rg][i][cg][3]};
                __builtin_nontemporal_store(v, &pred4[rb + cv]);
            }
        }
}

// ---------------------------------------------------------------------------
// 4) scatter-add ratings into label (duplicates sum correctly)
// ---------------------------------------------------------------------------
__global__ void scatter_kernel(const int* __restrict__ idx,
                               const float* __restrict__ r,
                               float* __restrict__ label, int nnz) {
    int k = blockIdx.x * blockDim.x + threadIdx.x;
    if (k < nnz) {
        int u  = idx[k];
        int it = idx[nnz + k];
        atomicAdd(&label[(size_t)u * NI + it], r[k]);
    }
}

extern "C" void kernel_launch(void* const* d_in, const int* in_sizes, int n_in,
                              void* d_out, int out_size, void* d_ws, size_t ws_size,
                              hipStream_t stream) {
    const float* A   = (const float*)d_in[0];
    const float* B   = (const float*)d_in[1];
    const int*   idx = (const int*)d_in[2];
    const float* r   = (const float*)d_in[3];
    const int nnz = in_sizes[3];

    float* out   = (float*)d_out;
    float* pred  = out;
    float* label = out + (size_t)NU * NI;
    float* ratio = out + 2 * (size_t)NU * NI;

    unsigned char* um = (unsigned char*)d_ws;
    unsigned char* im = um + NU;

    const int mask_words = (NU + NI) / 4;
    init_kernel<<<(mask_words + 255) / 256, 256, 0, stream>>>(
        (unsigned int*)d_ws, mask_words, ratio);
    build_masks_kernel<<<(nnz + 255) / 256, 256, 0, stream>>>(idx, um, im, nnz);

    dim3 grid(NI / TN, NU / TM);
    gemm_kernel<<<grid, 256, 0, stream>>>(A, B, um, im, pred, label);

    scatter_kernel<<<(nnz + 255) / 256, 256, 0, stream>>>(idx, r, label, nnz);
}